// Round 7
// baseline (678.110 us; speedup 1.0000x reference)
//
#include <hip/hip_runtime.h>

#define EPS_BN 1e-4f
constexpr int BLK = 256;
constexpr int ECAPC = 1856;  // coarse k-grouped-4 cap (27*64 padded max 1728)
constexpr int NCOPY = 8;     // stats atomic copies

// ---------- fine rulebook: row-major exact, stride 27 ----------
__global__ __launch_bounds__(64) void build_fine_k(
    const int* __restrict__ nbr, int n, int* __restrict__ cnt, int* __restrict__ ent) {
  int i = blockIdx.x * 64 + threadIdx.x;
  if (i >= n) return;
  int c = 0;
  const int* nr = nbr + (size_t)i * 27;
  int* er = ent + (size_t)i * 27;
#pragma unroll 1
  for (int k = 0; k < 27; ++k) {
    int j = nr[k];
    if (j >= 0) er[c++] = (k << 18) | j;
  }
  cnt[i] = c;
}

// ---------- coarse rulebook: k-grouped, padded to groups of 4 ----------
// entry = (r<<23)|(k<<18)|j ; pad = -1 (group tails only; first of group real)
__global__ __launch_bounds__(64) void build_subm4_k(
    const int* __restrict__ nbr, int n,
    int* __restrict__ segP, int* __restrict__ ent) {
  int T = blockIdx.x, r = threadIdx.x;
  int i = T * 64 + r;
  bool valid = i < n;
  int base = 0;
#pragma unroll 1
  for (int k = 0; k < 27; ++k) {
    int j = valid ? nbr[(size_t)i * 27 + k] : -1;
    bool act = j >= 0;
    unsigned long long mb = __ballot(act);
    int cntk = __popcll(mb);
    int pre = __popcll(mb & ((1ull << r) - 1));
    if (act) ent[(size_t)T * ECAPC + base + pre] = (r << 23) | (k << 18) | j;
    int padded = (cntk + 3) & ~3;
    if (r < padded - cntk) ent[(size_t)T * ECAPC + base + cntk + r] = -1;
    base += padded;
  }
  if (r == 0) segP[T] = base;
}

__global__ __launch_bounds__(BLK) void child_scatter_k(
    const int* __restrict__ parent, const int* __restrict__ offid, int n,
    int* __restrict__ ccnt, int* __restrict__ cent) {
  int i = blockIdx.x * BLK + threadIdx.x;
  if (i >= n) return;
  int p = parent[i];
  int slot = atomicAdd(&ccnt[p], 1);
  cent[p * 8 + slot] = i | (offid[i] << 25);
}

// ---------- Type A: output-stationary register-acc gather, fused input-BN ----------
// MODE 0: fine rulebook (ent stride 27, cnt per row); MODE 1: down (cent stride 8, ccnt);
// MODE 2: up (k=offid[row], j=parent[row]).  CAT: input = [inA|inB], lst covers both halves.
template <int CI, int CO, int MODE, bool CAT>
__global__ __launch_bounds__(BLK) void tconvA_k(
    const float* __restrict__ inA, const float* __restrict__ inB,
    const int* __restrict__ ent, const int* __restrict__ cnt,
    const int* __restrict__ parent, const int* __restrict__ offid,
    const float* __restrict__ sumsA, const float* __restrict__ sumsB,
    const float* __restrict__ gm, const float* __restrict__ bt, float invn,
    const float* __restrict__ W, float* __restrict__ out, int n,
    float* __restrict__ osums) {
  constexpr int LANES = CO / 4, SLOTS = BLK / LANES, RPS = 64 / SLOTS;
  constexpr int CIA = CAT ? CI / 2 : CI;
  __shared__ float red[2 * CO];
  __shared__ float lst[2 * CI];
  int t = threadIdx.x;
  if (t < CI) {
    float s = 0.f, q = 0.f;
    if (!CAT || t < CI / 2) {
#pragma unroll
      for (int cp = 0; cp < NCOPY; ++cp) { s += sumsA[cp * 2 * CIA + t]; q += sumsA[cp * 2 * CIA + CIA + t]; }
    } else {
      int c = t - CI / 2;
#pragma unroll
      for (int cp = 0; cp < NCOPY; ++cp) { s += sumsB[cp * 2 * CIA + c]; q += sumsB[cp * 2 * CIA + CIA + c]; }
    }
    float mu = s * invn, var = q * invn - mu * mu;
    float sc = gm[t] / sqrtf(var + EPS_BN);
    lst[t] = sc; lst[CI + t] = bt[t] - mu * sc;
  }
  for (int idx = t; idx < 2 * CO; idx += BLK) red[idx] = 0.f;
  __syncthreads();

  int slot = t / LANES, lane = t % LANES, g = lane * 4;
  int T = blockIdx.x;
  float ssum[4] = {0, 0, 0, 0}, ssq[4] = {0, 0, 0, 0};
#pragma unroll 1
  for (int rr = 0; rr < RPS; ++rr) {
    int row = T * 64 + slot * RPS + rr;
    bool vrow = row < n;
    float a0 = 0.f, a1 = 0.f, a2 = 0.f, a3 = 0.f;
    int ec = 0;
    if (vrow) ec = (MODE == 2) ? 1 : cnt[row];
#pragma unroll 1
    for (int e = 0; e < ec; ++e) {
      int k, j;
      if constexpr (MODE == 0) {
        int v = ent[(size_t)row * 27 + e];
        k = (v >> 18) & 31; j = v & 0x3FFFF;
      } else if constexpr (MODE == 1) {
        int v = ent[(size_t)row * 8 + e];
        k = v >> 25; j = v & 0x1FFFFFF;
      } else {
        k = offid[row]; j = parent[row];
      }
      const float* Wk = W + (size_t)k * (CI * CO) + g;
#pragma unroll
      for (int h = 0; h < CI / 32; ++h) {
        const float* xr;
        if constexpr (CAT) xr = (h == 0 ? inA : inB) + (size_t)j * CIA;
        else xr = inA + (size_t)j * CI + h * 32;
        float4 xv[8];
#pragma unroll
        for (int c4 = 0; c4 < 8; ++c4)
          xv[c4] = *reinterpret_cast<const float4*>(xr + c4 * 4);
#pragma unroll
        for (int c4 = 0; c4 < 8; ++c4) {
          int cb = h * 32 + c4 * 4;
          float4 sc4 = *reinterpret_cast<const float4*>(&lst[cb]);
          float4 sh4 = *reinterpret_cast<const float4*>(&lst[CI + cb]);
          float xs[4];
          xs[0] = fmaf(xv[c4].x, sc4.x, sh4.x);
          xs[1] = fmaf(xv[c4].y, sc4.y, sh4.y);
          xs[2] = fmaf(xv[c4].z, sc4.z, sh4.z);
          xs[3] = fmaf(xv[c4].w, sc4.w, sh4.w);
#pragma unroll
          for (int q = 0; q < 4; ++q) {
            float x = xs[q] > 0.f ? xs[q] : 0.f;
            float4 wv = *reinterpret_cast<const float4*>(Wk + (size_t)(cb + q) * CO);
            a0 = fmaf(x, wv.x, a0);
            a1 = fmaf(x, wv.y, a1);
            a2 = fmaf(x, wv.z, a2);
            a3 = fmaf(x, wv.w, a3);
          }
        }
      }
    }
    if (vrow)
      *reinterpret_cast<float4*>(out + (size_t)row * CO + g) = make_float4(a0, a1, a2, a3);
    ssum[0] += a0; ssum[1] += a1; ssum[2] += a2; ssum[3] += a3;
    ssq[0] = fmaf(a0, a0, ssq[0]); ssq[1] = fmaf(a1, a1, ssq[1]);
    ssq[2] = fmaf(a2, a2, ssq[2]); ssq[3] = fmaf(a3, a3, ssq[3]);
  }
#pragma unroll
  for (int q = 0; q < 4; ++q) {
    atomicAdd(&red[g + q], ssum[q]);
    atomicAdd(&red[CO + g + q], ssq[q]);
  }
  __syncthreads();
  int copy = blockIdx.x & (NCOPY - 1);
  if (t < 2 * CO) atomicAdd(&osums[copy * 2 * CO + t], red[t]);
}

// ---------- Type B v2: per-wave LDS X-staging, 1-deep pipeline, no in-loop barriers ----------
template <int CI, int CO>   // 64, 64
__global__ __launch_bounds__(BLK) void tconvB_k(
    const float* __restrict__ in, const int* __restrict__ segP,
    const int* __restrict__ ent, int ecap,
    const float* __restrict__ sums, const float* __restrict__ gm,
    const float* __restrict__ bt, float invn,
    const float* __restrict__ W, float* __restrict__ out, int n,
    float* __restrict__ osums) {
  constexpr int GO = CO / 16;   // 4
  constexpr int AP = CO + 4;
  __shared__ float lacc[64 * AP];
  __shared__ float lxs[4][2][16 * CI];   // [wave][buf][pair][ch]
  __shared__ int   lxe[4][2][16];
  __shared__ float lst[2 * CI];
  int t = threadIdx.x, T = blockIdx.x;
  if (t < CI) {
    float s = 0.f, q = 0.f;
#pragma unroll
    for (int cp = 0; cp < NCOPY; ++cp) { s += sums[cp * 2 * CI + t]; q += sums[cp * 2 * CI + CI + t]; }
    float mu = s * invn, var = q * invn - mu * mu;
    float sc = gm[t] / sqrtf(var + EPS_BN);
    lst[t] = sc; lst[CI + t] = bt[t] - mu * sc;
  }
  for (int idx = t; idx < 64 * AP; idx += BLK) lacc[idx] = 0.f;
  __syncthreads();

  int P = segP[T];
  const int* entT = ent + (size_t)T * ecap;
  int w = t >> 6, l = t & 63;
  int pr = l >> 2, cq = l & 3;          // staging role: pair, channel-quarter
  int sw = l >> 4, g = (l & 15) * GO;   // compute role: slot-in-wave, out-col base
  float* lx0 = lxs[w][0]; float* lx1 = lxs[w][1];
  int* le0 = lxe[w][0];   int* le1 = lxe[w][1];
  int ebase = w * 16;

  auto stageLoad = [&](int base, float4 xq[4], int& e16o, int& epo) {
    e16o = entT[base + (l & 15)];
    epo = entT[base + pr];
    int j = epo >= 0 ? (epo & 0x3FFFF) : 0;
    const float* xr = in + (size_t)j * CI + cq * 16;
#pragma unroll
    for (int q = 0; q < 4; ++q) xq[q] = *reinterpret_cast<const float4*>(xr + q * 4);
  };
  auto stageWrite = [&](float* lxn, int* lxen, const float4 xq[4], int e16, int ep) {
    if (l < 16) lxen[l] = e16;
#pragma unroll
    for (int q = 0; q < 4; ++q) {
      int cb = cq * 16 + q * 4;
      float4 sc4 = *reinterpret_cast<const float4*>(&lst[cb]);
      float4 sh4 = *reinterpret_cast<const float4*>(&lst[CI + cb]);
      float v0 = fmaf(xq[q].x, sc4.x, sh4.x);
      float v1 = fmaf(xq[q].y, sc4.y, sh4.y);
      float v2 = fmaf(xq[q].z, sc4.z, sh4.z);
      float v3 = fmaf(xq[q].w, sc4.w, sh4.w);
      v0 = (ep >= 0 && v0 > 0.f) ? v0 : 0.f;
      v1 = (ep >= 0 && v1 > 0.f) ? v1 : 0.f;
      v2 = (ep >= 0 && v2 > 0.f) ? v2 : 0.f;
      v3 = (ep >= 0 && v3 > 0.f) ? v3 : 0.f;
      *reinterpret_cast<float4*>(&lxn[pr * CI + cb]) = make_float4(v0, v1, v2, v3);
    }
  };

  if (ebase < P) {
    float4 xq[4]; int e16, ep;
    stageLoad(ebase, xq, e16, ep);
    stageWrite(lx0, le0, xq, e16, ep);
  }
  int cur = 0;
#pragma unroll 1
  for (int eb = ebase; eb < P; eb += 64) {
    int ebn = eb + 64;
    bool hasnext = ebn < P;
    float4 xq[4]; int e16n = -1, epn = -1;
    if (hasnext) stageLoad(ebn, xq, e16n, epn);   // issued before compute -> latency hidden
    const float* lxc = cur ? lx1 : lx0;
    const int* lxec = cur ? le1 : le0;
    if (eb + sw * 4 < P) {
      int e0 = lxec[sw * 4];
      int k = (e0 >> 18) & 31;
      const float* Wk = W + (size_t)k * (CI * CO) + g;
      int rr4[4];
      float acc[4][GO];
#pragma unroll
      for (int pp = 0; pp < 4; ++pp) {
        int ev = lxec[sw * 4 + pp];
        rr4[pp] = ev >= 0 ? ((ev >> 23) & 63) : -1;
#pragma unroll
        for (int b = 0; b < GO; ++b) acc[pp][b] = 0.f;
      }
#pragma unroll 4
      for (int c4 = 0; c4 < CI / 4; ++c4) {
        int cb = c4 * 4;
        float xs[4][4];
#pragma unroll
        for (int pp = 0; pp < 4; ++pp) {
          float4 xv = *reinterpret_cast<const float4*>(&lxc[(sw * 4 + pp) * CI + cb]);
          xs[pp][0] = xv.x; xs[pp][1] = xv.y; xs[pp][2] = xv.z; xs[pp][3] = xv.w;
        }
#pragma unroll
        for (int q = 0; q < 4; ++q) {
          float4 w4 = *reinterpret_cast<const float4*>(Wk + (size_t)(cb + q) * CO);
          float wv[4] = {w4.x, w4.y, w4.z, w4.w};
#pragma unroll
          for (int pp = 0; pp < 4; ++pp)
#pragma unroll
            for (int b = 0; b < GO; ++b)
              acc[pp][b] = fmaf(xs[pp][q], wv[b], acc[pp][b]);
        }
      }
#pragma unroll
      for (int pp = 0; pp < 4; ++pp) {
        if (rr4[pp] >= 0) {
          float* ap = &lacc[rr4[pp] * AP + g];
#pragma unroll
          for (int b = 0; b < GO; ++b) atomicAdd(ap + b, acc[pp][b]);
        }
      }
    }
    if (hasnext) {
      float* lxn = cur ? lx0 : lx1;
      int* lxen = cur ? le0 : le1;
      stageWrite(lxn, lxen, xq, e16n, epn);
    }
    cur ^= 1;
  }
  __syncthreads();

  // epilogue: coalesced store + fused per-channel stats
  for (int idx = t; idx < 64 * (CO / 4); idx += BLK) {
    int r = idx / (CO / 4), c4 = idx - r * (CO / 4);
    int row = T * 64 + r;
    if (row < n)
      *reinterpret_cast<float4*>(out + (size_t)row * CO + c4 * 4) =
          *reinterpret_cast<const float4*>(&lacc[r * AP + c4 * 4]);
  }
  int copy = blockIdx.x & (NCOPY - 1);
  if (t < CO) {
    float s = 0.f, ss = 0.f;
#pragma unroll 4
    for (int r = 0; r < 64; ++r) {
      float x = lacc[r * AP + t];
      s += x; ss = fmaf(x, x, ss);
    }
    atomicAdd(&osums[copy * 2 * CO + t], s);
    atomicAdd(&osums[copy * 2 * CO + CO + t], ss);
  }
}

// ---------------- conv_in: [N,3] x [27,3,32] -> [N,32], fused stats ----------------
__global__ __launch_bounds__(BLK) void conv_in_k(
    const float* __restrict__ feat, const int* __restrict__ nbr,
    const float* __restrict__ W, float* __restrict__ out, int n,
    float* __restrict__ osums) {
  int i = blockIdx.x * BLK + threadIdx.x;
  bool valid = i < n;
  float acc[32];
#pragma unroll
  for (int c = 0; c < 32; ++c) acc[c] = 0.f;
#pragma unroll 1
  for (int k = 0; k < 27; ++k) {
    int j = valid ? nbr[(size_t)i * 27 + k] : -1;
    if (j < 0) continue;
    float x0 = feat[j * 3 + 0], x1 = feat[j * 3 + 1], x2 = feat[j * 3 + 2];
    const float* w0 = W + k * 96;
#pragma unroll
    for (int co = 0; co < 8; ++co) {
      float4 a = *reinterpret_cast<const float4*>(w0 + co * 4);
      float4 b = *reinterpret_cast<const float4*>(w0 + 32 + co * 4);
      float4 cc = *reinterpret_cast<const float4*>(w0 + 64 + co * 4);
      acc[4*co+0] = fmaf(x0, a.x, fmaf(x1, b.x, fmaf(x2, cc.x, acc[4*co+0])));
      acc[4*co+1] = fmaf(x0, a.y, fmaf(x1, b.y, fmaf(x2, cc.y, acc[4*co+1])));
      acc[4*co+2] = fmaf(x0, a.z, fmaf(x1, b.z, fmaf(x2, cc.z, acc[4*co+2])));
      acc[4*co+3] = fmaf(x0, a.w, fmaf(x1, b.w, fmaf(x2, cc.w, acc[4*co+3])));
    }
  }
  if (valid) {
    float* o = out + (size_t)i * 32;
#pragma unroll
    for (int co = 0; co < 8; ++co)
      *reinterpret_cast<float4*>(o + co * 4) = make_float4(acc[4*co], acc[4*co+1], acc[4*co+2], acc[4*co+3]);
  }
  __shared__ float red[2][4][32];
  int w = threadIdx.x >> 6;
#pragma unroll
  for (int c = 0; c < 32; ++c) {
    float v = acc[c], q = acc[c] * acc[c];
#pragma unroll
    for (int off = 32; off; off >>= 1) {
      v += __shfl_down(v, off);
      q += __shfl_down(q, off);
    }
    if ((threadIdx.x & 63) == 0) { red[0][w][c] = v; red[1][w][c] = q; }
  }
  __syncthreads();
  if (threadIdx.x < 64) {
    int kind = threadIdx.x >> 5, c = threadIdx.x & 31;
    float s = red[kind][0][c] + red[kind][1][c] + red[kind][2][c] + red[kind][3][c];
    atomicAdd(&osums[(blockIdx.x & (NCOPY - 1)) * 64 + kind * 32 + c], s);
  }
}

// ---------------- head: finalize + bn @ w_lin + b_lin -> [N,50] ----------------
__global__ __launch_bounds__(BLK) void head_k(
    const float* __restrict__ fin, const float* __restrict__ sums,
    const float* __restrict__ gm, const float* __restrict__ bt, float inv_n,
    const float* __restrict__ Wl, const float* __restrict__ bl,
    float* __restrict__ out, int n) {
  __shared__ float lw[32 * 50];
  __shared__ float lb[52];
  __shared__ float lst[64];
  int t = threadIdx.x;
  if (t < 32) {
    float s = 0.f, q = 0.f;
#pragma unroll
    for (int cp = 0; cp < NCOPY; ++cp) { s += sums[cp * 64 + t]; q += sums[cp * 64 + 32 + t]; }
    float mu = s * inv_n, var = q * inv_n - mu * mu;
    float sc = gm[t] / sqrtf(var + EPS_BN);
    lst[t] = sc; lst[32 + t] = bt[t] - mu * sc;
  }
  for (int idx = t; idx < 1600; idx += BLK) lw[idx] = Wl[idx];
  if (t < 50) lb[t] = bl[t];
  __syncthreads();
  int i = blockIdx.x * BLK + t;
  if (i >= n) return;
  float x[32];
  const float* fj = fin + (size_t)i * 32;
#pragma unroll
  for (int c4 = 0; c4 < 8; ++c4) {
    float4 v = *reinterpret_cast<const float4*>(fj + c4 * 4);
    float vs[4] = {v.x, v.y, v.z, v.w};
#pragma unroll
    for (int q = 0; q < 4; ++q) {
      int c = c4 * 4 + q;
      float y = fmaf(vs[q], lst[c], lst[32 + c]);
      x[c] = y > 0.f ? y : 0.f;
    }
  }
  float acc[50];
#pragma unroll
  for (int co = 0; co < 50; ++co) acc[co] = lb[co];
#pragma unroll 4
  for (int c = 0; c < 32; ++c) {
#pragma unroll
    for (int co = 0; co < 50; ++co) acc[co] = fmaf(x[c], lw[c * 50 + co], acc[co]);
  }
  float* o = out + (size_t)i * 50;
#pragma unroll
  for (int co = 0; co < 25; ++co)
    *reinterpret_cast<float2*>(o + co * 2) = make_float2(acc[co * 2], acc[co * 2 + 1]);
}

extern "C" void kernel_launch(void* const* d_in, const int* in_sizes, int n_in,
                              void* d_out, int out_size, void* d_ws, size_t ws_size,
                              hipStream_t stream) {
  const float* feat   = (const float*)d_in[1];
  const int*   nbrF   = (const int*)d_in[2];
  const int*   nbrC   = (const int*)d_in[3];
  const int*   parent = (const int*)d_in[4];
  const int*   offid  = (const int*)d_in[5];
  const float* w_in   = (const float*)d_in[7];
  const float* w_b1   = (const float*)d_in[8];
  const float* w_down = (const float*)d_in[9];
  const float* w_b2   = (const float*)d_in[10];
  const float* w_up   = (const float*)d_in[11];
  const float* w_b3   = (const float*)d_in[12];
  const float* g1v = (const float*)d_in[13], *b1v = (const float*)d_in[14];
  const float* gdv = (const float*)d_in[15], *bdv = (const float*)d_in[16];
  const float* g2v = (const float*)d_in[17], *b2v = (const float*)d_in[18];
  const float* guv = (const float*)d_in[19], *buv = (const float*)d_in[20];
  const float* g3v = (const float*)d_in[21], *b3v = (const float*)d_in[22];
  const float* gov = (const float*)d_in[23], *bov = (const float*)d_in[24];
  const float* w_lin = (const float*)d_in[25];
  const float* b_lin = (const float*)d_in[26];
  float* out = (float*)d_out;

  int N  = in_sizes[4];
  int NC = in_sizes[3] / 27;
  int ntF = (N + 63) / 64, ntC = (NC + 63) / 64;

  float* ws = (float*)d_ws;
  float* B1 = ws;                       // f1 [N,32] -> g2c [NC,64] -> f3 [N,32]
  float* B2 = B1 + (size_t)N * 64;      // f2 [N,32]
  float* B3 = B2 + (size_t)N * 32;      // gC [NC,64] -> u [N,32]
  float* sums1 = B3 + (size_t)N * 64;   // 8*64
  float* sumsD = sums1 + 8 * 64;        // 8*64
  float* sums2 = sumsD + 8 * 64;        // 8*128
  float* sumsU = sums2 + 8 * 128;       // 8*128
  float* sums4 = sumsU + 8 * 128;       // 8*64
  float* sums5 = sums4 + 8 * 64;        // 8*64
  int* ccnt = (int*)(sums5 + 8 * 64);         // NC
  int* cent = ccnt + NC;                      // NC*8
  int* cntF = cent + (size_t)NC * 8;          // N
  int* entF = cntF + N;                       // N*27
  int* segPC = entF + (size_t)N * 27;         // ntC
  int* entC  = segPC + ntC;                   // ntC*ECAPC

  hipMemsetAsync(sums1, 0, (4096 + NC) * sizeof(float), stream);

  int gridN = (N + BLK - 1) / BLK;
  float invN = 1.f / (float)N, invC = 1.f / (float)NC;

  // rulebooks
  build_fine_k<<<ntF, 64, 0, stream>>>(nbrF, N, cntF, entF);
  build_subm4_k<<<ntC, 64, 0, stream>>>(nbrC, NC, segPC, entC);
  child_scatter_k<<<gridN, BLK, 0, stream>>>(parent, offid, N, ccnt, cent);

  // conv_in -> f1(B1), stats -> sums1
  conv_in_k<<<gridN, BLK, 0, stream>>>(feat, nbrF, w_in, B1, N, sums1);

  // b1: bn1(f1) -> f2(B2), stats -> sumsD
  tconvA_k<32, 32, 0, false><<<ntF, BLK, 0, stream>>>(
      B1, nullptr, entF, cntF, nullptr, nullptr,
      sums1, nullptr, g1v, b1v, invN, w_b1, B2, N, sumsD);

  // down: bnD(f2) -> gC(B3), stats -> sums2
  tconvA_k<32, 64, 1, false><<<ntC, BLK, 0, stream>>>(
      B2, nullptr, cent, ccnt, nullptr, nullptr,
      sumsD, nullptr, gdv, bdv, invN, w_down, B3, NC, sums2);

  // b2: bn2(gC) -> g2c(B1, f1 dead), stats -> sumsU
  tconvB_k<64, 64><<<ntC, BLK, 0, stream>>>(
      B3, segPC, entC, ECAPC, sums2, g2v, b2v, invC, w_b2, B1, NC, sumsU);

  // up: bnU(g2c) -> u(B3, gC dead), stats -> sums4
  tconvA_k<64, 32, 2, false><<<ntF, BLK, 0, stream>>>(
      B1, nullptr, nullptr, nullptr, parent, offid,
      sumsU, nullptr, guv, buv, invC, w_up, B3, N, sums4);

  // b3: [bn3a(f2)|bn3b(u)] -> f3(B1, g2c dead), stats -> sums5
  tconvA_k<64, 32, 0, true><<<ntF, BLK, 0, stream>>>(
      B2, B3, entF, cntF, nullptr, nullptr,
      sumsD, sums4, g3v, b3v, invN, w_b3, B1, N, sums5);

  head_k<<<gridN, BLK, 0, stream>>>(B1, sums5, gov, bov, invN, w_lin, b_lin, out, N);
}

// Round 8
// 552.798 us; speedup vs baseline: 1.2267x; 1.2267x over previous
//
#include <hip/hip_runtime.h>

#define EPS_BN 1e-4f
constexpr int BLK = 256;
constexpr int ECAPC = 1856;  // coarse k-grouped-4 cap (27*64 + pads)
constexpr int NCOPY = 8;     // stats atomic copies

// ---------- fine rulebook: row-major exact, stride 27 ----------
__global__ __launch_bounds__(64) void build_fine_k(
    const int* __restrict__ nbr, int n, int* __restrict__ cnt, int* __restrict__ ent) {
  int i = blockIdx.x * 64 + threadIdx.x;
  if (i >= n) return;
  int c = 0;
  const int* nr = nbr + (size_t)i * 27;
  int* er = ent + (size_t)i * 27;
#pragma unroll 1
  for (int k = 0; k < 27; ++k) {
    int j = nr[k];
    if (j >= 0) er[c++] = (k << 18) | j;
  }
  cnt[i] = c;
}

// ---------- coarse rulebook: k-grouped, padded to groups of 4 ----------
// entry = (r<<23)|(k<<18)|j ; pad = -1 (group tails only; first of group real)
__global__ __launch_bounds__(64) void build_subm4_k(
    const int* __restrict__ nbr, int n,
    int* __restrict__ segP, int* __restrict__ ent) {
  int T = blockIdx.x, r = threadIdx.x;
  int i = T * 64 + r;
  bool valid = i < n;
  int base = 0;
#pragma unroll 1
  for (int k = 0; k < 27; ++k) {
    int j = valid ? nbr[(size_t)i * 27 + k] : -1;
    bool act = j >= 0;
    unsigned long long mb = __ballot(act);
    int cntk = __popcll(mb);
    int pre = __popcll(mb & ((1ull << r) - 1));
    if (act) ent[(size_t)T * ECAPC + base + pre] = (r << 23) | (k << 18) | j;
    int padded = (cntk + 3) & ~3;
    if (r < padded - cntk) ent[(size_t)T * ECAPC + base + cntk + r] = -1;
    base += padded;
  }
  if (r == 0) segP[T] = base;
}

__global__ __launch_bounds__(BLK) void child_scatter_k(
    const int* __restrict__ parent, const int* __restrict__ offid, int n,
    int* __restrict__ ccnt, int* __restrict__ cent) {
  int i = blockIdx.x * BLK + threadIdx.x;
  if (i >= n) return;
  int p = parent[i];
  int slot = atomicAdd(&ccnt[p], 1);
  cent[p * 8 + slot] = i | (offid[i] << 25);
}

// ---------- Type A (R6-proven): output-stationary register-acc gather ----------
// MODE 0: fine rulebook (stride 27 + cnt); MODE 1: down (cent stride 8, ccnt);
// MODE 2: up (k=offid[row], j=parent[row], 1 entry)
template <int CI, int CO, int MODE>
__global__ __launch_bounds__(BLK) void tconvA_k(
    const float* __restrict__ in, const int* __restrict__ ent, const int* __restrict__ cnt,
    const int* __restrict__ parent, const int* __restrict__ offid,
    const float* __restrict__ W, float* __restrict__ out, int n,
    float* __restrict__ osums) {
  constexpr int LANES = CO / 4, SLOTS = BLK / LANES, RPS = 64 / SLOTS;
  __shared__ float red[2 * CO];
  int t = threadIdx.x;
  for (int idx = t; idx < 2 * CO; idx += BLK) red[idx] = 0.f;
  __syncthreads();
  int slot = t / LANES, lane = t % LANES, g = lane * 4;
  int T = blockIdx.x;
  float ssum[4] = {0, 0, 0, 0}, ssq[4] = {0, 0, 0, 0};
#pragma unroll 1
  for (int rr = 0; rr < RPS; ++rr) {
    int row = T * 64 + slot * RPS + rr;
    bool vrow = row < n;
    float a0 = 0.f, a1 = 0.f, a2 = 0.f, a3 = 0.f;
    int ec = 0;
    if (vrow) ec = (MODE == 2) ? 1 : cnt[row];
#pragma unroll 1
    for (int e = 0; e < ec; ++e) {
      int k, j;
      if constexpr (MODE == 0) {
        int v = ent[(size_t)row * 27 + e];
        k = (v >> 18) & 31; j = v & 0x3FFFF;
      } else if constexpr (MODE == 1) {
        int v = ent[(size_t)row * 8 + e];
        k = v >> 25; j = v & 0x1FFFFFF;
      } else {
        k = offid[row]; j = parent[row];
      }
      const float* Wk = W + (size_t)k * (CI * CO) + g;
      const float* xr = in + (size_t)j * CI;
#pragma unroll
      for (int h = 0; h < CI / 32; ++h) {
        float4 xv[8];
#pragma unroll
        for (int c4 = 0; c4 < 8; ++c4)
          xv[c4] = *reinterpret_cast<const float4*>(xr + h * 32 + c4 * 4);
#pragma unroll
        for (int c4 = 0; c4 < 8; ++c4) {
          float xs[4] = {xv[c4].x, xv[c4].y, xv[c4].z, xv[c4].w};
#pragma unroll
          for (int q = 0; q < 4; ++q) {
            float4 wv = *reinterpret_cast<const float4*>(Wk + (size_t)(h * 32 + c4 * 4 + q) * CO);
            a0 = fmaf(xs[q], wv.x, a0);
            a1 = fmaf(xs[q], wv.y, a1);
            a2 = fmaf(xs[q], wv.z, a2);
            a3 = fmaf(xs[q], wv.w, a3);
          }
        }
      }
    }
    if (vrow)
      *reinterpret_cast<float4*>(out + (size_t)row * CO + g) = make_float4(a0, a1, a2, a3);
    ssum[0] += a0; ssum[1] += a1; ssum[2] += a2; ssum[3] += a3;
    ssq[0] = fmaf(a0, a0, ssq[0]); ssq[1] = fmaf(a1, a1, ssq[1]);
    ssq[2] = fmaf(a2, a2, ssq[2]); ssq[3] = fmaf(a3, a3, ssq[3]);
  }
#pragma unroll
  for (int q = 0; q < 4; ++q) {
    atomicAdd(&red[g + q], ssum[q]);
    atomicAdd(&red[CO + g + q], ssq[q]);
  }
  __syncthreads();
  int copy = blockIdx.x & (NCOPY - 1);
  if (t < 2 * CO) atomicAdd(&osums[copy * 2 * CO + t], red[t]);
}

// ---------- Type B v3: chunked LDS X-stage (pad 66, BN fused at stage), flat k-groups ----------
template <int CI, int CO>   // 64, 64
__global__ __launch_bounds__(BLK) void tconvB_k(
    const float* __restrict__ in, const int* __restrict__ segP,
    const int* __restrict__ ent, int ecap,
    const float* __restrict__ sums, const float* __restrict__ gm,
    const float* __restrict__ bt, float invn,
    const float* __restrict__ W, float* __restrict__ out, int n,
    float* __restrict__ osums) {
  constexpr int AP = CO + 2;      // 66: conflict-light acc
  constexpr int XP = CI + 2;      // 66: conflict-light x rows
  constexpr int CHUNK = 128;      // pairs per staged chunk (multiple of 4)
  __shared__ float lacc[64 * AP];
  __shared__ float lx[CHUNK * XP];
  __shared__ int   lent[CHUNK];
  __shared__ float lst[2 * CI];
  int t = threadIdx.x, T = blockIdx.x;
  if (t < CI) {
    float s = 0.f, q = 0.f;
#pragma unroll
    for (int cp = 0; cp < NCOPY; ++cp) { s += sums[cp * 2 * CI + t]; q += sums[cp * 2 * CI + CI + t]; }
    float mu = s * invn, var = q * invn - mu * mu;
    float sc = gm[t] / sqrtf(var + EPS_BN);
    lst[t] = sc; lst[CI + t] = bt[t] - mu * sc;
  }
  for (int idx = t; idx < 64 * AP; idx += BLK) lacc[idx] = 0.f;
  int P = segP[T];
  const int* entT = ent + (size_t)T * ecap;
  int slot = t >> 4, g = (t & 15) * 4;
  __syncthreads();

#pragma unroll 1
  for (int c0 = 0; c0 < P; c0 += CHUNK) {
    int lim = min(P - c0, CHUNK);
    // stage entries + X rows (BN+ReLU applied once per pair here)
    if (t < CHUNK) lent[t] = (t < lim) ? entT[c0 + t] : -1;
    for (int idx = t; idx < CHUNK * 16; idx += BLK) {
      int pr = idx >> 4, cq = idx & 15;
      int ev = (pr < lim) ? entT[c0 + pr] : -1;
      float4 v = make_float4(0.f, 0.f, 0.f, 0.f);
      if (ev >= 0) {
        int j = ev & 0x3FFFF;
        float4 x = *reinterpret_cast<const float4*>(in + (size_t)j * CI + cq * 4);
        int cb = cq * 4;
        float y0 = fmaf(x.x, lst[cb + 0], lst[CI + cb + 0]);
        float y1 = fmaf(x.y, lst[cb + 1], lst[CI + cb + 1]);
        float y2 = fmaf(x.z, lst[cb + 2], lst[CI + cb + 2]);
        float y3 = fmaf(x.w, lst[cb + 3], lst[CI + cb + 3]);
        v = make_float4(y0 > 0.f ? y0 : 0.f, y1 > 0.f ? y1 : 0.f,
                        y2 > 0.f ? y2 : 0.f, y3 > 0.f ? y3 : 0.f);
      }
      *reinterpret_cast<float4*>(&lx[pr * XP + cq * 4]) = v;
    }
    __syncthreads();
    // compute: 4-pair groups, same k per group
#pragma unroll 1
    for (int gr = slot; gr * 4 < lim; gr += 16) {
      int p0 = gr * 4;
      int e0 = lent[p0];
      int k = (e0 >> 18) & 31;
      const float* Wk = W + (size_t)k * (CI * CO) + g;
      int rr[4];
      float acc[4][4];
#pragma unroll
      for (int pp = 0; pp < 4; ++pp) {
        int ev = lent[p0 + pp];
        rr[pp] = ev >= 0 ? ((ev >> 23) & 63) : -1;
        acc[pp][0] = acc[pp][1] = acc[pp][2] = acc[pp][3] = 0.f;
      }
#pragma unroll 4
      for (int c4 = 0; c4 < CI / 4; ++c4) {
        int cb = c4 * 4;
        float xs[4][4];
#pragma unroll
        for (int pp = 0; pp < 4; ++pp) {
          float4 xv = *reinterpret_cast<const float4*>(&lx[(p0 + pp) * XP + cb]);
          xs[pp][0] = xv.x; xs[pp][1] = xv.y; xs[pp][2] = xv.z; xs[pp][3] = xv.w;
        }
#pragma unroll
        for (int q = 0; q < 4; ++q) {
          float4 w4 = *reinterpret_cast<const float4*>(Wk + (size_t)(cb + q) * CO);
#pragma unroll
          for (int pp = 0; pp < 4; ++pp) {
            acc[pp][0] = fmaf(xs[pp][q], w4.x, acc[pp][0]);
            acc[pp][1] = fmaf(xs[pp][q], w4.y, acc[pp][1]);
            acc[pp][2] = fmaf(xs[pp][q], w4.z, acc[pp][2]);
            acc[pp][3] = fmaf(xs[pp][q], w4.w, acc[pp][3]);
          }
        }
      }
#pragma unroll
      for (int pp = 0; pp < 4; ++pp) {
        if (rr[pp] >= 0) {
          float* ap = &lacc[rr[pp] * AP + g];
          atomicAdd(ap + 0, acc[pp][0]);
          atomicAdd(ap + 1, acc[pp][1]);
          atomicAdd(ap + 2, acc[pp][2]);
          atomicAdd(ap + 3, acc[pp][3]);
        }
      }
    }
    __syncthreads();
  }

  // epilogue: coalesced store + fused per-channel stats
  for (int idx = t; idx < 64 * (CO / 4); idx += BLK) {
    int r = idx / (CO / 4), c4 = idx - r * (CO / 4);
    int row = T * 64 + r;
    if (row < n)
      *reinterpret_cast<float4*>(out + (size_t)row * CO + c4 * 4) =
          *reinterpret_cast<const float4*>(&lacc[r * AP + c4 * 4]);
  }
  int copy = blockIdx.x & (NCOPY - 1);
  if (t < CO) {
    float s = 0.f, ss = 0.f;
#pragma unroll 4
    for (int r = 0; r < 64; ++r) {
      float x = lacc[r * AP + t];
      s += x; ss = fmaf(x, x, ss);
    }
    atomicAdd(&osums[copy * 2 * CO + t], s);
    atomicAdd(&osums[copy * 2 * CO + CO + t], ss);
  }
}

// ---------- bnact: finalize(8 copies) + relu(x*scale+shift) ----------
template <int C>
__global__ __launch_bounds__(BLK) void bnact_k(
    const float* __restrict__ in, const float* __restrict__ sums,
    const float* __restrict__ gm, const float* __restrict__ bt, float invn,
    float* __restrict__ outp, int n) {
  __shared__ float lst[2 * C];
  int t = threadIdx.x;
  if (t < C) {
    float s = 0.f, q = 0.f;
#pragma unroll
    for (int cp = 0; cp < NCOPY; ++cp) { s += sums[cp * 2 * C + t]; q += sums[cp * 2 * C + C + t]; }
    float mu = s * invn, var = q * invn - mu * mu;
    float sc = gm[t] / sqrtf(var + EPS_BN);
    lst[t] = sc; lst[C + t] = bt[t] - mu * sc;
  }
  __syncthreads();
  int total = n * (C / 4);
  const float4* in4 = reinterpret_cast<const float4*>(in);
  float4* out4 = reinterpret_cast<float4*>(outp);
  for (int idx = blockIdx.x * BLK + t; idx < total; idx += gridDim.x * BLK) {
    int cb = (idx & (C / 4 - 1)) * 4;
    float4 x = in4[idx];
    float v[4] = {x.x, x.y, x.z, x.w};
#pragma unroll
    for (int q = 0; q < 4; ++q) {
      float y = fmaf(v[q], lst[cb + q], lst[C + cb + q]);
      v[q] = y > 0.f ? y : 0.f;
    }
    out4[idx] = make_float4(v[0], v[1], v[2], v[3]);
  }
}

// ---------- bncat: concat(bn(f2), bn(u)) -> acat [N,64] ----------
__global__ __launch_bounds__(BLK) void bncat_k(
    const float* __restrict__ fa, const float* __restrict__ sA,
    const float* __restrict__ gA, const float* __restrict__ bA,
    const float* __restrict__ fb, const float* __restrict__ sB,
    const float* __restrict__ gB, const float* __restrict__ bB,
    float invn, float* __restrict__ acat, int n) {
  __shared__ float lst[128];
  int t = threadIdx.x;
  if (t < 64) {
    int half = t >> 5, c = t & 31;
    const float* ss = half ? sB : sA;
    const float* gg = half ? gB : gA;
    const float* bb = half ? bB : bA;
    float s = 0.f, q = 0.f;
#pragma unroll
    for (int cp = 0; cp < NCOPY; ++cp) { s += ss[cp * 64 + c]; q += ss[cp * 64 + 32 + c]; }
    float mu = s * invn, var = q * invn - mu * mu;
    float sc = gg[c] / sqrtf(var + EPS_BN);
    lst[half * 64 + c] = sc; lst[half * 64 + 32 + c] = bb[c] - mu * sc;
  }
  __syncthreads();
  int total = n * 16;
  for (int idx = blockIdx.x * BLK + t; idx < total; idx += gridDim.x * BLK) {
    int row = idx >> 4, c4 = idx & 15;
    int half = c4 >> 3, cc = (c4 & 7) * 4;
    const float* src = half ? fb : fa;
    float4 x = *reinterpret_cast<const float4*>(src + (size_t)row * 32 + cc);
    const float* L = lst + half * 64;
    float v[4] = {x.x, x.y, x.z, x.w};
#pragma unroll
    for (int q = 0; q < 4; ++q) {
      float y = fmaf(v[q], L[cc + q], L[32 + cc + q]);
      v[q] = y > 0.f ? y : 0.f;
    }
    *reinterpret_cast<float4*>(acat + (size_t)row * 64 + c4 * 4) = make_float4(v[0], v[1], v[2], v[3]);
  }
}

// ---------------- conv_in: [N,3] x [27,3,32] -> [N,32], fused stats ----------------
__global__ __launch_bounds__(BLK) void conv_in_k(
    const float* __restrict__ feat, const int* __restrict__ nbr,
    const float* __restrict__ W, float* __restrict__ out, int n,
    float* __restrict__ osums) {
  int i = blockIdx.x * BLK + threadIdx.x;
  bool valid = i < n;
  float acc[32];
#pragma unroll
  for (int c = 0; c < 32; ++c) acc[c] = 0.f;
#pragma unroll 1
  for (int k = 0; k < 27; ++k) {
    int j = valid ? nbr[(size_t)i * 27 + k] : -1;
    if (j < 0) continue;
    float x0 = feat[j * 3 + 0], x1 = feat[j * 3 + 1], x2 = feat[j * 3 + 2];
    const float* w0 = W + k * 96;
#pragma unroll
    for (int co = 0; co < 8; ++co) {
      float4 a = *reinterpret_cast<const float4*>(w0 + co * 4);
      float4 b = *reinterpret_cast<const float4*>(w0 + 32 + co * 4);
      float4 cc = *reinterpret_cast<const float4*>(w0 + 64 + co * 4);
      acc[4*co+0] = fmaf(x0, a.x, fmaf(x1, b.x, fmaf(x2, cc.x, acc[4*co+0])));
      acc[4*co+1] = fmaf(x0, a.y, fmaf(x1, b.y, fmaf(x2, cc.y, acc[4*co+1])));
      acc[4*co+2] = fmaf(x0, a.z, fmaf(x1, b.z, fmaf(x2, cc.z, acc[4*co+2])));
      acc[4*co+3] = fmaf(x0, a.w, fmaf(x1, b.w, fmaf(x2, cc.w, acc[4*co+3])));
    }
  }
  if (valid) {
    float* o = out + (size_t)i * 32;
#pragma unroll
    for (int co = 0; co < 8; ++co)
      *reinterpret_cast<float4*>(o + co * 4) = make_float4(acc[4*co], acc[4*co+1], acc[4*co+2], acc[4*co+3]);
  }
  __shared__ float red[2][4][32];
  int w = threadIdx.x >> 6;
#pragma unroll
  for (int c = 0; c < 32; ++c) {
    float v = acc[c], q = acc[c] * acc[c];
#pragma unroll
    for (int off = 32; off; off >>= 1) {
      v += __shfl_down(v, off);
      q += __shfl_down(q, off);
    }
    if ((threadIdx.x & 63) == 0) { red[0][w][c] = v; red[1][w][c] = q; }
  }
  __syncthreads();
  if (threadIdx.x < 64) {
    int kind = threadIdx.x >> 5, c = threadIdx.x & 31;
    float s = red[kind][0][c] + red[kind][1][c] + red[kind][2][c] + red[kind][3][c];
    atomicAdd(&osums[(blockIdx.x & (NCOPY - 1)) * 64 + kind * 32 + c], s);
  }
}

// ---------------- head: finalize(8 copies) + bn @ w_lin + b_lin -> [N,50] ----------------
__global__ __launch_bounds__(BLK) void head_k(
    const float* __restrict__ fin, const float* __restrict__ sums,
    const float* __restrict__ gm, const float* __restrict__ bt, float inv_n,
    const float* __restrict__ Wl, const float* __restrict__ bl,
    float* __restrict__ out, int n) {
  __shared__ float lw[32 * 50];
  __shared__ float lb[52];
  __shared__ float lst[64];
  int t = threadIdx.x;
  if (t < 32) {
    float s = 0.f, q = 0.f;
#pragma unroll
    for (int cp = 0; cp < NCOPY; ++cp) { s += sums[cp * 64 + t]; q += sums[cp * 64 + 32 + t]; }
    float mu = s * inv_n, var = q * inv_n - mu * mu;
    float sc = gm[t] / sqrtf(var + EPS_BN);
    lst[t] = sc; lst[32 + t] = bt[t] - mu * sc;
  }
  for (int idx = t; idx < 1600; idx += BLK) lw[idx] = Wl[idx];
  if (t < 50) lb[t] = bl[t];
  __syncthreads();
  int i = blockIdx.x * BLK + t;
  if (i >= n) return;
  float x[32];
  const float* fj = fin + (size_t)i * 32;
#pragma unroll
  for (int c4 = 0; c4 < 8; ++c4) {
    float4 v = *reinterpret_cast<const float4*>(fj + c4 * 4);
    float vs[4] = {v.x, v.y, v.z, v.w};
#pragma unroll
    for (int q = 0; q < 4; ++q) {
      int c = c4 * 4 + q;
      float y = fmaf(vs[q], lst[c], lst[32 + c]);
      x[c] = y > 0.f ? y : 0.f;
    }
  }
  float acc[50];
#pragma unroll
  for (int co = 0; co < 50; ++co) acc[co] = lb[co];
#pragma unroll 4
  for (int c = 0; c < 32; ++c) {
#pragma unroll
    for (int co = 0; co < 50; ++co) acc[co] = fmaf(x[c], lw[c * 50 + co], acc[co]);
  }
  float* o = out + (size_t)i * 50;
#pragma unroll
  for (int co = 0; co < 25; ++co)
    *reinterpret_cast<float2*>(o + co * 2) = make_float2(acc[co * 2], acc[co * 2 + 1]);
}

extern "C" void kernel_launch(void* const* d_in, const int* in_sizes, int n_in,
                              void* d_out, int out_size, void* d_ws, size_t ws_size,
                              hipStream_t stream) {
  const float* feat   = (const float*)d_in[1];
  const int*   nbrF   = (const int*)d_in[2];
  const int*   nbrC   = (const int*)d_in[3];
  const int*   parent = (const int*)d_in[4];
  const int*   offid  = (const int*)d_in[5];
  const float* w_in   = (const float*)d_in[7];
  const float* w_b1   = (const float*)d_in[8];
  const float* w_down = (const float*)d_in[9];
  const float* w_b2   = (const float*)d_in[10];
  const float* w_up   = (const float*)d_in[11];
  const float* w_b3   = (const float*)d_in[12];
  const float* g1v = (const float*)d_in[13], *b1v = (const float*)d_in[14];
  const float* gdv = (const float*)d_in[15], *bdv = (const float*)d_in[16];
  const float* g2v = (const float*)d_in[17], *b2v = (const float*)d_in[18];
  const float* guv = (const float*)d_in[19], *buv = (const float*)d_in[20];
  const float* g3v = (const float*)d_in[21], *b3v = (const float*)d_in[22];
  const float* gov = (const float*)d_in[23], *bov = (const float*)d_in[24];
  const float* w_lin = (const float*)d_in[25];
  const float* b_lin = (const float*)d_in[26];
  float* out = (float*)d_out;

  int N  = in_sizes[4];
  int NC = in_sizes[3] / 27;
  int ntF = (N + 63) / 64, ntC = (NC + 63) / 64;

  size_t szF = (size_t)N * 32;
  size_t szG = (size_t)NC * 64;
  size_t SB  = (size_t)N * 64;

  float* ws = (float*)d_ws;
  float* S1 = ws;          // f1 [N,32] -> g2c [NC,64]
  float* S2 = S1 + SB;     // a1 -> acat [N,64]
  float* S3 = S2 + SB;     // f2 [N,32] -> f3 [N,32]
  float* S4 = S3 + szF;    // a2 [N,32] -> u [N,32]
  float* S5 = S4 + szF;    // gC [NC,64] -> au [NC,64]
  float* sums1 = S5 + szG;           // 8*64
  float* sumsD = sums1 + 8 * 64;     // 8*64
  float* sums2 = sumsD + 8 * 64;     // 8*128
  float* sumsU = sums2 + 8 * 128;    // 8*128
  float* sums4 = sumsU + 8 * 128;    // 8*64
  float* sums5 = sums4 + 8 * 64;     // 8*64
  int* ccnt = (int*)(sums5 + 8 * 64);         // NC
  int* cent = ccnt + NC;                      // NC*8
  int* cntF = cent + (size_t)NC * 8;          // N
  int* entF = cntF + N;                       // N*27
  int* segPC = entF + (size_t)N * 27;         // ntC
  int* entC  = segPC + ntC;                   // ntC*ECAPC

  hipMemsetAsync(sums1, 0, (4096 + NC) * sizeof(float), stream);

  int gridN = (N + BLK - 1) / BLK;
  int agrid = 1024;
  float invN = 1.f / (float)N, invC = 1.f / (float)NC;

  // rulebooks
  build_fine_k<<<ntF, 64, 0, stream>>>(nbrF, N, cntF, entF);
  build_subm4_k<<<ntC, 64, 0, stream>>>(nbrC, NC, segPC, entC);
  child_scatter_k<<<gridN, BLK, 0, stream>>>(parent, offid, N, ccnt, cent);

  // conv_in -> f1(S1), stats -> sums1
  conv_in_k<<<gridN, BLK, 0, stream>>>(feat, nbrF, w_in, S1, N, sums1);
  bnact_k<32><<<agrid, BLK, 0, stream>>>(S1, sums1, g1v, b1v, invN, S2, N);   // a1

  // b1: a1 -> f2(S3), stats -> sumsD
  tconvA_k<32, 32, 0><<<ntF, BLK, 0, stream>>>(
      S2, entF, cntF, nullptr, nullptr, w_b1, S3, N, sumsD);
  bnact_k<32><<<agrid, BLK, 0, stream>>>(S3, sumsD, gdv, bdv, invN, S4, N);   // a2

  // down: a2 -> gC(S5), stats -> sums2
  tconvA_k<32, 64, 1><<<ntC, BLK, 0, stream>>>(
      S4, cent, ccnt, nullptr, nullptr, w_down, S5, NC, sums2);

  // b2: bn2(gC) fused at stage -> g2c(S1, f1 dead), stats -> sumsU
  tconvB_k<64, 64><<<ntC, BLK, 0, stream>>>(
      S5, segPC, entC, ECAPC, sums2, g2v, b2v, invC, w_b2, S1, NC, sumsU);
  bnact_k<64><<<agrid, BLK, 0, stream>>>(S1, sumsU, guv, buv, invC, S5, NC);  // au (gC dead)

  // up: au -> u(S4, a2 dead), stats -> sums4
  tconvA_k<64, 32, 2><<<ntF, BLK, 0, stream>>>(
      S5, nullptr, nullptr, parent, offid, w_up, S4, N, sums4);

  // bncat: (bn(f2)|bn(u)) -> acat(S2, a1 dead)
  bncat_k<<<agrid, BLK, 0, stream>>>(
      S3, sumsD, g3v, b3v, S4, sums4, g3v + 32, b3v + 32, invN, S2, N);

  // b3: acat -> f3(S3, f2 dead), stats -> sums5
  tconvA_k<64, 32, 0><<<ntF, BLK, 0, stream>>>(
      S2, entF, cntF, nullptr, nullptr, w_b3, S3, N, sums5);

  head_k<<<gridN, BLK, 0, stream>>>(S3, sums5, gov, bov, invN, w_lin, b_lin, out, N);
}